// Round 1
// baseline (10481.058 us; speedup 1.0000x reference)
//
#include <hip/hip_runtime.h>
#include <hip/hip_bf16.h>
#include <stdint.h>

#define TT 512
#define BB 256
#define DD 512
#define HH 256
#define AA 32
#define NG 1024  // 4*H

using f32x4 = __attribute__((ext_vector_type(4))) float;
using bf8   = __attribute__((ext_vector_type(8))) short;

static __device__ __forceinline__ short f2bf(float f) {
  union { float f; uint32_t u; } v; v.f = f;
  uint32_t u = v.u;
  u = u + 0x7fffu + ((u >> 16) & 1u);   // round-to-nearest-even
  return (short)(u >> 16);
}
static __device__ __forceinline__ float bf2f(unsigned short s) {
  union { uint32_t u; float f; } v; v.u = ((uint32_t)s) << 16;
  return v.f;
}
static __device__ __forceinline__ float sigf(float x) {
  return 1.0f / (1.0f + __expf(-x));
}
static __device__ __forceinline__ float tanh_(float x) {
  float e = __expf(2.0f * x);
  return 1.0f - 2.0f / (e + 1.0f);   // safe at +/-inf
}

// ---- workspace layout ----
static constexpr size_t XP_OFF    = 0;                              // bf16 [T*B][1024]
static constexpr size_t XP_BYTES  = (size_t)TT * BB * NG * 2;       // 268435456
static constexpr size_t WXT_OFF   = XP_OFF + XP_BYTES;              // bf16 [1024][512]
static constexpr size_t WXT_BYTES = (size_t)NG * DD * 2;            // 1048576
static constexpr size_t HBUF_OFF  = WXT_OFF + WXT_BYTES;            // bf16 [2][B][H]
static constexpr size_t HBUF_BYTES= (size_t)2 * BB * HH * 2;        // 262144
static constexpr size_t CNT_OFF   = HBUF_OFF + HBUF_BYTES;          // 16 groups x 64 uints
static constexpr size_t CNT_BYTES = 16 * 64 * 4;
static constexpr size_t WS_NEEDED = CNT_OFF + CNT_BYTES;

__global__ void init_sync_kernel(unsigned int* cnt) {
  int i = threadIdx.x;
  #pragma unroll
  for (int j = 0; j < 4; ++j) cnt[j * 256 + i] = 0;
}

// Wx [512][1024] fp32 -> WxT [1024][512] bf16
__global__ __launch_bounds__(256) void transpose_wx_kernel(
    const float* __restrict__ Wx, unsigned short* __restrict__ WxT) {
  __shared__ float tile[32][33];
  int bx = blockIdx.x;
  int k0 = (bx & 15) * 32;
  int n0 = (bx >> 4) * 32;
  int r = threadIdx.x >> 5;
  int c = threadIdx.x & 31;
  #pragma unroll
  for (int i = 0; i < 4; ++i) {
    int rr = r + i * 8;
    tile[rr][c] = Wx[(size_t)(k0 + rr) * NG + n0 + c];
  }
  __syncthreads();
  #pragma unroll
  for (int i = 0; i < 4; ++i) {
    int rr = r + i * 8;
    WxT[(size_t)(n0 + rr) * DD + k0 + c] = (unsigned short)f2bf(tile[c][rr]);
  }
}

// xp[M=131072][1024] bf16 = X[M][512] @ Wx[512][1024] + b
__global__ __launch_bounds__(256) void gemm_xproj(
    const float* __restrict__ X,
    const unsigned short* __restrict__ WxT,  // [n][k] bf16
    const float* __restrict__ bias,
    unsigned short* __restrict__ xp) {
  __shared__ short As[128][72];  // [m][k], +8 pad -> 2-way-free banks
  __shared__ short Bs[128][72];  // [n][k]
  const int tid  = threadIdx.x;
  const int lane = tid & 63;
  const int wave = tid >> 6;
  const int quad = lane >> 4;
  const int l15  = lane & 15;
  const int wm = wave >> 1, wn = wave & 1;
  const int bid = blockIdx.x;
  const int m0 = (bid >> 3) * 128;   // consecutive bids share m-tile -> L3 reuse of X
  const int n0 = (bid & 7) * 128;

  f32x4 acc[4][4];
  #pragma unroll
  for (int i = 0; i < 4; ++i)
    #pragma unroll
    for (int j = 0; j < 4; ++j) acc[i][j] = (f32x4){0.f, 0.f, 0.f, 0.f};

  for (int kt = 0; kt < 8; ++kt) {
    const int k0 = kt * 64;
    #pragma unroll
    for (int jj = 0; jj < 4; ++jj) {
      int c = tid + jj * 256;         // 1024 16B-chunks
      int row = c >> 3;
      int kc = (c & 7) * 8;
      const float4* src = (const float4*)(X + (size_t)(m0 + row) * DD + k0 + kc);
      float4 v0 = src[0];
      float4 v1 = src[1];
      bf8 tv;
      tv[0] = f2bf(v0.x); tv[1] = f2bf(v0.y); tv[2] = f2bf(v0.z); tv[3] = f2bf(v0.w);
      tv[4] = f2bf(v1.x); tv[5] = f2bf(v1.y); tv[6] = f2bf(v1.z); tv[7] = f2bf(v1.w);
      *(bf8*)&As[row][kc] = tv;
      const uint4* bsrc = (const uint4*)(WxT + (size_t)(n0 + row) * DD + k0 + kc);
      *(uint4*)&Bs[row][kc] = *bsrc;
    }
    __syncthreads();
    #pragma unroll
    for (int ks = 0; ks < 2; ++ks) {
      bf8 a[4], b[4];
      #pragma unroll
      for (int mt = 0; mt < 4; ++mt)
        a[mt] = *(const bf8*)&As[wm * 64 + mt * 16 + l15][ks * 32 + quad * 8];
      #pragma unroll
      for (int nt = 0; nt < 4; ++nt)
        b[nt] = *(const bf8*)&Bs[wn * 64 + nt * 16 + l15][ks * 32 + quad * 8];
      #pragma unroll
      for (int mt = 0; mt < 4; ++mt)
        #pragma unroll
        for (int nt = 0; nt < 4; ++nt)
          acc[mt][nt] = __builtin_amdgcn_mfma_f32_16x16x32_bf16(a[mt], b[nt], acc[mt][nt], 0, 0, 0);
    }
    __syncthreads();
  }
  #pragma unroll
  for (int mt = 0; mt < 4; ++mt)
    #pragma unroll
    for (int nt = 0; nt < 4; ++nt) {
      int col = n0 + wn * 64 + nt * 16 + l15;
      float bv = bias[col];
      #pragma unroll
      for (int r = 0; r < 4; ++r) {
        int row = m0 + wm * 64 + mt * 16 + quad * 4 + r;  // C/D: row=quad*4+reg, col=lane&15
        xp[(size_t)row * NG + col] = (unsigned short)f2bf(acc[mt][nt][r] + bv);
      }
    }
}

// Persistent scan: 256 blocks = 16 batch-groups x 16 j-slices, 64 thr/block.
// Block (grp,g): batch rows [16*grp,16*grp+16), h-cols [16*g,16*g+16),
// z-cols {g*16+jj + 256*gate}. Gate-aligned n-tiles -> elementwise epilogue.
__global__ __launch_bounds__(64, 1) void scan_kernel(
    const unsigned short* __restrict__ xp,
    const int* __restrict__ is_new,
    const float* __restrict__ carry_c,
    const float* __restrict__ carry_h,
    const float* __restrict__ Wh,
    const float* __restrict__ Wa,
    const float* __restrict__ ba,
    const float* __restrict__ Wv,
    const float* __restrict__ bv,
    float* __restrict__ out,
    unsigned short* __restrict__ h_buf,
    unsigned int* __restrict__ cnt) {
  const int tid  = threadIdx.x;
  const int quad = tid >> 4;
  const int l15  = tid & 15;
  const int bid  = blockIdx.x;
  const int g    = bid & 15;
  const int grp  = bid >> 4;
  const int b0   = grp * 16;
  const int j0   = g * 16;

  __shared__ short h_lds[16][264];  // bf16, +8 pad
  __shared__ int flag_lds[16];

  // ---- loop-invariant Wh B-fragments -> 128 VGPRs ----
  bf8 whb[4][8];
  #pragma unroll
  for (int nt = 0; nt < 4; ++nt)
    #pragma unroll
    for (int ks = 0; ks < 8; ++ks)
      #pragma unroll
      for (int j = 0; j < 8; ++j) {
        int k = ks * 32 + quad * 8 + j;            // B-frag: k = quad*8+j, n = lane&15
        int col = nt * 256 + j0 + l15;
        whb[nt][ks][j] = f2bf(Wh[(size_t)k * NG + col]);
      }
  // ---- Wa/Wv B-fragments (head GEMM), cols astart..astart+ncols-1 of 33 ----
  const int astart = (g < 15) ? (2 * g) : 30;
  const int ncols  = (g < 15) ? 2 : 3;
  bf8 wab[8];
  #pragma unroll
  for (int ks = 0; ks < 8; ++ks)
    #pragma unroll
    for (int j = 0; j < 8; ++j) {
      int k = ks * 32 + quad * 8 + j;
      float v = 0.0f;
      if (l15 < ncols) {
        int a = astart + l15;
        v = (a < 32) ? Wa[(size_t)k * 32 + a] : Wv[k];
      }
      wab[ks][j] = f2bf(v);
    }
  float obias = 0.0f;
  if (l15 < ncols) {
    int a = astart + l15;
    obias = (a < 32) ? ba[a] : bv[0];
  }
  // ---- carry c in registers (C-layout: b = quad*4+r, j = j0+l15) ----
  float c4[4];
  #pragma unroll
  for (int r = 0; r < 4; ++r)
    c4[r] = carry_c[(size_t)(b0 + quad * 4 + r) * HH + j0 + l15];

  unsigned int* cptr = &cnt[grp * 64];

  #pragma unroll 1
  for (int t = 0; t <= TT; ++t) {
    const bool last = (t == TT);
    unsigned short xpraw[16];
    if (!last) {
      // prefetch xp + reset flags before the spin (independent of h)
      #pragma unroll
      for (int nt = 0; nt < 4; ++nt)
        #pragma unroll
        for (int r = 0; r < 4; ++r) {
          size_t row = (size_t)t * BB + b0 + quad * 4 + r;
          xpraw[nt * 4 + r] = xp[row * NG + nt * 256 + j0 + l15];
        }
      if (tid < 16) flag_lds[tid] = is_new[t * BB + b0 + tid];
    }
    if (t > 0) {
      unsigned int tgt = 16u * (unsigned int)t;
      int guard = 0;
      while (__hip_atomic_load(cptr, __ATOMIC_ACQUIRE, __HIP_MEMORY_SCOPE_AGENT) < tgt) {
        __builtin_amdgcn_s_sleep(1);
        if (++guard > (1 << 26)) break;   // anti-hang bailout
      }
    }
    __syncthreads();
    // ---- stage full h rows (UNmasked; reset applied later) ----
    if (t == 0) {
      #pragma unroll
      for (int i = 0; i < 64; ++i) {
        int flat = i * 64 + tid;
        int row = flat >> 8, k = flat & 255;
        h_lds[row][k] = f2bf(carry_h[(size_t)(b0 + row) * HH + k]);
      }
    } else {
      const unsigned int* hb = (const unsigned int*)(h_buf + (size_t)(t & 1) * (BB * HH));
      #pragma unroll
      for (int i = 0; i < 32; ++i) {
        int flat = i * 64 + tid;             // coalesced agent-scope loads
        int row = flat >> 7, k2 = flat & 127;
        unsigned int vv = __hip_atomic_load(&hb[(b0 + row) * 128 + k2],
                                            __ATOMIC_RELAXED, __HIP_MEMORY_SCOPE_AGENT);
        *(unsigned int*)&h_lds[row][k2 * 2] = vv;
      }
    }
    __syncthreads();
    // ---- A-fragments of h (m = lane&15 = batch row, k = quad*8+j) ----
    bf8 af[8];
    #pragma unroll
    for (int ks = 0; ks < 8; ++ks)
      af[ks] = *(const bf8*)&h_lds[l15][ks * 32 + quad * 8];
    // ---- heads for step t-1 (uses pre-reset h = new_h[t-1]) ----
    if (t > 0) {
      f32x4 oacc = {0.f, 0.f, 0.f, 0.f};
      #pragma unroll
      for (int ks = 0; ks < 8; ++ks)
        oacc = __builtin_amdgcn_mfma_f32_16x16x32_bf16(af[ks], wab[ks], oacc, 0, 0, 0);
      if (l15 < ncols) {
        #pragma unroll
        for (int r = 0; r < 4; ++r) {
          size_t orow = (size_t)(t - 1) * BB + b0 + quad * 4 + r;
          out[orow * 33 + astart + l15] = oacc[r] + obias;
        }
      }
    }
    if (last) break;
    // ---- episode reset on h ----
    int mreset = flag_lds[l15];
    if (mreset) {
      #pragma unroll
      for (int ks = 0; ks < 8; ++ks)
        #pragma unroll
        for (int j = 0; j < 8; ++j) af[ks][j] = 0;
    }
    // ---- z = h @ Wh (4 gate-aligned n-tiles) ----
    f32x4 zacc[4];
    #pragma unroll
    for (int nt = 0; nt < 4; ++nt) zacc[nt] = (f32x4){0.f, 0.f, 0.f, 0.f};
    #pragma unroll
    for (int ks = 0; ks < 8; ++ks)
      #pragma unroll
      for (int nt = 0; nt < 4; ++nt)
        zacc[nt] = __builtin_amdgcn_mfma_f32_16x16x32_bf16(af[ks], whb[nt][ks], zacc[nt], 0, 0, 0);
    // ---- gates (all four gates of (b,j) live in the same lane/reg) ----
    unsigned short* hnext = h_buf + (size_t)((t + 1) & 1) * (BB * HH);
    #pragma unroll
    for (int r = 0; r < 4; ++r) {
      int fr = flag_lds[quad * 4 + r];
      float zi = zacc[0][r] + bf2f(xpraw[0 * 4 + r]);
      float zf = zacc[1][r] + bf2f(xpraw[1 * 4 + r]);
      float zg = zacc[2][r] + bf2f(xpraw[2 * 4 + r]);
      float zo = zacc[3][r] + bf2f(xpraw[3 * 4 + r]);
      float ce = fr ? 0.0f : c4[r];
      float ncv = sigf(zf) * ce + sigf(zi) * tanh_(zg);
      c4[r] = ncv;
      float nh = sigf(zo) * tanh_(ncv);
      unsigned short hv = (unsigned short)f2bf(nh);
      __hip_atomic_store(&hnext[(size_t)(b0 + quad * 4 + r) * HH + j0 + l15], hv,
                         __ATOMIC_RELAXED, __HIP_MEMORY_SCOPE_AGENT);
    }
    __syncthreads();  // drains vmcnt(0): all lanes' h stores at coherence point
    if (tid == 0)
      __hip_atomic_fetch_add(cptr, 1u, __ATOMIC_RELEASE, __HIP_MEMORY_SCOPE_AGENT);
  }
}

extern "C" void kernel_launch(void* const* d_in, const int* in_sizes, int n_in,
                              void* d_out, int out_size, void* d_ws, size_t ws_size,
                              hipStream_t stream) {
  const float* X       = (const float*)d_in[0];
  const int* is_new    = (const int*)d_in[1];
  const float* carry_c = (const float*)d_in[2];
  const float* carry_h = (const float*)d_in[3];
  const float* Wx      = (const float*)d_in[4];
  const float* Wh      = (const float*)d_in[5];
  const float* b       = (const float*)d_in[6];
  const float* Wa      = (const float*)d_in[7];
  const float* ba      = (const float*)d_in[8];
  const float* Wv      = (const float*)d_in[9];
  const float* bv      = (const float*)d_in[10];
  float* out = (float*)d_out;
  char* ws = (char*)d_ws;
  if (ws_size < WS_NEEDED) return;  // diagnostic: out stays poisoned
  unsigned short* xp   = (unsigned short*)(ws + XP_OFF);
  unsigned short* WxT  = (unsigned short*)(ws + WXT_OFF);
  unsigned short* hbuf = (unsigned short*)(ws + HBUF_OFF);
  unsigned int* cnt    = (unsigned int*)(ws + CNT_OFF);

  hipLaunchKernelGGL(init_sync_kernel, dim3(1), dim3(256), 0, stream, cnt);
  hipLaunchKernelGGL(transpose_wx_kernel, dim3(512), dim3(256), 0, stream, Wx, WxT);
  hipLaunchKernelGGL(gemm_xproj, dim3(8192), dim3(256), 0, stream, X, WxT, b, xp);
  hipLaunchKernelGGL(scan_kernel, dim3(256), dim3(64), 0, stream,
                     xp, is_new, carry_c, carry_h, Wh, Wa, ba, Wv, bv, out, hbuf, cnt);
}

// Round 2
// 4268.549 us; speedup vs baseline: 2.4554x; 2.4554x over previous
//
#include <hip/hip_runtime.h>
#include <hip/hip_bf16.h>
#include <stdint.h>

#define TT 512
#define BB 256
#define DD 512
#define HH 256
#define AA 32
#define NG 1024  // 4*H

using f32x4 = __attribute__((ext_vector_type(4))) float;
using bf8   = __attribute__((ext_vector_type(8))) short;

static __device__ __forceinline__ short f2bf(float f) {
  union { float f; uint32_t u; } v; v.f = f;
  uint32_t u = v.u;
  u = u + 0x7fffu + ((u >> 16) & 1u);   // round-to-nearest-even
  return (short)(u >> 16);
}
static __device__ __forceinline__ float bf2f(unsigned short s) {
  union { uint32_t u; float f; } v; v.u = ((uint32_t)s) << 16;
  return v.f;
}
static __device__ __forceinline__ float sigf(float x) {
  return 1.0f / (1.0f + __expf(-x));
}
static __device__ __forceinline__ float tanh_(float x) {
  float e = __expf(2.0f * x);
  return 1.0f - 2.0f / (e + 1.0f);   // safe at +/-inf
}

// ---- workspace layout ----
static constexpr size_t XP_OFF    = 0;                              // bf16 [T*B][1024]
static constexpr size_t XP_BYTES  = (size_t)TT * BB * NG * 2;       // 268435456
static constexpr size_t WXT_OFF   = XP_OFF + XP_BYTES;              // bf16 [1024][512]
static constexpr size_t WXT_BYTES = (size_t)NG * DD * 2;            // 1048576
static constexpr size_t HBUF_OFF  = WXT_OFF + WXT_BYTES;            // bf16 [2][B][H]
static constexpr size_t HBUF_BYTES= (size_t)2 * BB * HH * 2;        // 262144
static constexpr size_t CNT_OFF   = HBUF_OFF + HBUF_BYTES;          // 16 groups x 64 uints
static constexpr size_t CNT_BYTES = 16 * 64 * 4;
static constexpr size_t WS_NEEDED = CNT_OFF + CNT_BYTES;

__global__ void init_sync_kernel(unsigned int* cnt) {
  int i = threadIdx.x;
  #pragma unroll
  for (int j = 0; j < 4; ++j) cnt[j * 256 + i] = 0;
}

// Wx [512][1024] fp32 -> WxT [1024][512] bf16
__global__ __launch_bounds__(256) void transpose_wx_kernel(
    const float* __restrict__ Wx, unsigned short* __restrict__ WxT) {
  __shared__ float tile[32][33];
  int bx = blockIdx.x;
  int k0 = (bx & 15) * 32;
  int n0 = (bx >> 4) * 32;
  int r = threadIdx.x >> 5;
  int c = threadIdx.x & 31;
  #pragma unroll
  for (int i = 0; i < 4; ++i) {
    int rr = r + i * 8;
    tile[rr][c] = Wx[(size_t)(k0 + rr) * NG + n0 + c];
  }
  __syncthreads();
  #pragma unroll
  for (int i = 0; i < 4; ++i) {
    int rr = r + i * 8;
    WxT[(size_t)(n0 + rr) * DD + k0 + c] = (unsigned short)f2bf(tile[c][rr]);
  }
}

// xp[M=131072][1024] bf16 = X[M][512] @ Wx[512][1024] + b
__global__ __launch_bounds__(256) void gemm_xproj(
    const float* __restrict__ X,
    const unsigned short* __restrict__ WxT,  // [n][k] bf16
    const float* __restrict__ bias,
    unsigned short* __restrict__ xp) {
  __shared__ short As[128][72];  // [m][k], +8 pad -> 2-way-free banks
  __shared__ short Bs[128][72];  // [n][k]
  const int tid  = threadIdx.x;
  const int lane = tid & 63;
  const int wave = tid >> 6;
  const int quad = lane >> 4;
  const int l15  = lane & 15;
  const int wm = wave >> 1, wn = wave & 1;
  const int bid = blockIdx.x;
  const int m0 = (bid >> 3) * 128;   // consecutive bids share m-tile -> L3 reuse of X
  const int n0 = (bid & 7) * 128;

  f32x4 acc[4][4];
  #pragma unroll
  for (int i = 0; i < 4; ++i)
    #pragma unroll
    for (int j = 0; j < 4; ++j) acc[i][j] = (f32x4){0.f, 0.f, 0.f, 0.f};

  for (int kt = 0; kt < 8; ++kt) {
    const int k0 = kt * 64;
    #pragma unroll
    for (int jj = 0; jj < 4; ++jj) {
      int c = tid + jj * 256;         // 1024 16B-chunks
      int row = c >> 3;
      int kc = (c & 7) * 8;
      const float4* src = (const float4*)(X + (size_t)(m0 + row) * DD + k0 + kc);
      float4 v0 = src[0];
      float4 v1 = src[1];
      bf8 tv;
      tv[0] = f2bf(v0.x); tv[1] = f2bf(v0.y); tv[2] = f2bf(v0.z); tv[3] = f2bf(v0.w);
      tv[4] = f2bf(v1.x); tv[5] = f2bf(v1.y); tv[6] = f2bf(v1.z); tv[7] = f2bf(v1.w);
      *(bf8*)&As[row][kc] = tv;
      const uint4* bsrc = (const uint4*)(WxT + (size_t)(n0 + row) * DD + k0 + kc);
      *(uint4*)&Bs[row][kc] = *bsrc;
    }
    __syncthreads();
    #pragma unroll
    for (int ks = 0; ks < 2; ++ks) {
      bf8 a[4], b[4];
      #pragma unroll
      for (int mt = 0; mt < 4; ++mt)
        a[mt] = *(const bf8*)&As[wm * 64 + mt * 16 + l15][ks * 32 + quad * 8];
      #pragma unroll
      for (int nt = 0; nt < 4; ++nt)
        b[nt] = *(const bf8*)&Bs[wn * 64 + nt * 16 + l15][ks * 32 + quad * 8];
      #pragma unroll
      for (int mt = 0; mt < 4; ++mt)
        #pragma unroll
        for (int nt = 0; nt < 4; ++nt)
          acc[mt][nt] = __builtin_amdgcn_mfma_f32_16x16x32_bf16(a[mt], b[nt], acc[mt][nt], 0, 0, 0);
    }
    __syncthreads();
  }
  #pragma unroll
  for (int mt = 0; mt < 4; ++mt)
    #pragma unroll
    for (int nt = 0; nt < 4; ++nt) {
      int col = n0 + wn * 64 + nt * 16 + l15;
      float bv = bias[col];
      #pragma unroll
      for (int r = 0; r < 4; ++r) {
        int row = m0 + wm * 64 + mt * 16 + quad * 4 + r;  // C/D: row=quad*4+reg, col=lane&15
        xp[(size_t)row * NG + col] = (unsigned short)f2bf(acc[mt][nt][r] + bv);
      }
    }
}

// Persistent scan: 256 blocks = 16 batch-groups x 16 j-slices, 64 thr/block.
// ALL cross-block traffic (h_buf, cnt) uses RELAXED agent-scope atomics:
// they bypass L2 and are served by the coherent memory-side L3, so no
// acquire/release fences (buffer_inv / buffer_wbl2 = full-L2 inv/writeback
// per op on gfx95x -- the round-1 10ms pathology) are needed. Ordering:
// producer drains h-stores via __syncthreads()'s s_waitcnt vmcnt(0) before
// the counter add; consumer's h-loads are data-dependent on the spin exit.
__global__ __launch_bounds__(64, 1) void scan_kernel(
    const unsigned short* __restrict__ xp,
    const int* __restrict__ is_new,
    const float* __restrict__ carry_c,
    const float* __restrict__ carry_h,
    const float* __restrict__ Wh,
    const float* __restrict__ Wa,
    const float* __restrict__ ba,
    const float* __restrict__ Wv,
    const float* __restrict__ bv,
    float* __restrict__ out,
    unsigned short* __restrict__ h_buf,
    unsigned int* __restrict__ cnt) {
  const int tid  = threadIdx.x;
  const int quad = tid >> 4;
  const int l15  = tid & 15;
  const int bid  = blockIdx.x;
  const int g    = bid & 15;
  const int grp  = bid >> 4;
  const int b0   = grp * 16;
  const int j0   = g * 16;

  __shared__ short h_lds[16][264];  // bf16, +8 pad
  __shared__ int flag_lds[16];

  // ---- loop-invariant Wh B-fragments -> 128 VGPRs ----
  bf8 whb[4][8];
  #pragma unroll
  for (int nt = 0; nt < 4; ++nt)
    #pragma unroll
    for (int ks = 0; ks < 8; ++ks)
      #pragma unroll
      for (int j = 0; j < 8; ++j) {
        int k = ks * 32 + quad * 8 + j;            // B-frag: k = quad*8+j, n = lane&15
        int col = nt * 256 + j0 + l15;
        whb[nt][ks][j] = f2bf(Wh[(size_t)k * NG + col]);
      }
  // ---- Wa/Wv B-fragments (head GEMM), cols astart..astart+ncols-1 of 33 ----
  const int astart = (g < 15) ? (2 * g) : 30;
  const int ncols  = (g < 15) ? 2 : 3;
  bf8 wab[8];
  #pragma unroll
  for (int ks = 0; ks < 8; ++ks)
    #pragma unroll
    for (int j = 0; j < 8; ++j) {
      int k = ks * 32 + quad * 8 + j;
      float v = 0.0f;
      if (l15 < ncols) {
        int a = astart + l15;
        v = (a < 32) ? Wa[(size_t)k * 32 + a] : Wv[k];
      }
      wab[ks][j] = f2bf(v);
    }
  float obias = 0.0f;
  if (l15 < ncols) {
    int a = astart + l15;
    obias = (a < 32) ? ba[a] : bv[0];
  }
  // ---- carry c in registers (C-layout: b = quad*4+r, j = j0+l15) ----
  float c4[4];
  #pragma unroll
  for (int r = 0; r < 4; ++r)
    c4[r] = carry_c[(size_t)(b0 + quad * 4 + r) * HH + j0 + l15];

  unsigned int* cptr = &cnt[grp * 64];

  #pragma unroll 1
  for (int t = 0; t <= TT; ++t) {
    const bool last = (t == TT);
    unsigned short xpraw[16];
    if (!last) {
      // prefetch xp + reset flags before the spin (independent of h)
      #pragma unroll
      for (int nt = 0; nt < 4; ++nt)
        #pragma unroll
        for (int r = 0; r < 4; ++r) {
          size_t row = (size_t)t * BB + b0 + quad * 4 + r;
          xpraw[nt * 4 + r] = xp[row * NG + nt * 256 + j0 + l15];
        }
      if (tid < 16) flag_lds[tid] = is_new[t * BB + b0 + tid];
    }
    if (t > 0) {
      unsigned int tgt = 16u * (unsigned int)t;
      int guard = 0;
      // RELAXED spin: no per-poll L2 invalidate
      while (__hip_atomic_load(cptr, __ATOMIC_RELAXED, __HIP_MEMORY_SCOPE_AGENT) < tgt) {
        __builtin_amdgcn_s_sleep(1);
        if (++guard > (1 << 26)) break;   // anti-hang bailout
      }
      __atomic_signal_fence(__ATOMIC_ACQUIRE);  // compiler-only: no load hoisting
    }
    __syncthreads();
    // ---- stage full h rows (UNmasked; reset applied later) ----
    if (t == 0) {
      #pragma unroll
      for (int i = 0; i < 64; ++i) {
        int flat = i * 64 + tid;
        int row = flat >> 8, k = flat & 255;
        h_lds[row][k] = f2bf(carry_h[(size_t)(b0 + row) * HH + k]);
      }
    } else {
      const unsigned long long* hb =
          (const unsigned long long*)(h_buf + (size_t)(t & 1) * (BB * HH));
      #pragma unroll
      for (int i = 0; i < 16; ++i) {
        int flat = i * 64 + tid;             // coalesced 8B agent-scope loads
        int row = flat >> 6, k4 = flat & 63; // 64 x 8B per row of 512B
        unsigned long long vv = __hip_atomic_load(&hb[(b0 + row) * 64 + k4],
                                                  __ATOMIC_RELAXED, __HIP_MEMORY_SCOPE_AGENT);
        *(unsigned long long*)&h_lds[row][k4 * 4] = vv;
      }
    }
    __syncthreads();
    // ---- A-fragments of h (m = lane&15 = batch row, k = quad*8+j) ----
    bf8 af[8];
    #pragma unroll
    for (int ks = 0; ks < 8; ++ks)
      af[ks] = *(const bf8*)&h_lds[l15][ks * 32 + quad * 8];
    // ---- heads MFMA for step t-1 (uses pre-reset h = new_h[t-1]) ----
    f32x4 oacc = {0.f, 0.f, 0.f, 0.f};
    if (t > 0) {
      #pragma unroll
      for (int ks = 0; ks < 8; ++ks)
        oacc = __builtin_amdgcn_mfma_f32_16x16x32_bf16(af[ks], wab[ks], oacc, 0, 0, 0);
    }
    if (!last) {
      // ---- episode reset on h (separate copy: heads used un-reset af) ----
      bf8 afr[8];
      int mreset = flag_lds[l15];
      #pragma unroll
      for (int ks = 0; ks < 8; ++ks) {
        afr[ks] = af[ks];
        if (mreset)
          #pragma unroll
          for (int j = 0; j < 8; ++j) afr[ks][j] = 0;
      }
      // ---- z = h @ Wh (4 gate-aligned n-tiles) ----
      f32x4 zacc[4];
      #pragma unroll
      for (int nt = 0; nt < 4; ++nt) zacc[nt] = (f32x4){0.f, 0.f, 0.f, 0.f};
      #pragma unroll
      for (int ks = 0; ks < 8; ++ks)
        #pragma unroll
        for (int nt = 0; nt < 4; ++nt)
          zacc[nt] = __builtin_amdgcn_mfma_f32_16x16x32_bf16(afr[ks], whb[nt][ks], zacc[nt], 0, 0, 0);
      // ---- gates (all four gates of (b,j) live in the same lane/reg) ----
      unsigned short* hnext = h_buf + (size_t)((t + 1) & 1) * (BB * HH);
      #pragma unroll
      for (int r = 0; r < 4; ++r) {
        int fr = flag_lds[quad * 4 + r];
        float zi = zacc[0][r] + bf2f(xpraw[0 * 4 + r]);
        float zf = zacc[1][r] + bf2f(xpraw[1 * 4 + r]);
        float zg = zacc[2][r] + bf2f(xpraw[2 * 4 + r]);
        float zo = zacc[3][r] + bf2f(xpraw[3 * 4 + r]);
        float ce = fr ? 0.0f : c4[r];
        float ncv = sigf(zf) * ce + sigf(zi) * tanh_(zg);
        c4[r] = ncv;
        float nh = sigf(zo) * tanh_(ncv);
        unsigned short hv = (unsigned short)f2bf(nh);
        __hip_atomic_store(&hnext[(size_t)(b0 + quad * 4 + r) * HH + j0 + l15], hv,
                           __ATOMIC_RELAXED, __HIP_MEMORY_SCOPE_AGENT);
      }
      // Drain h-stores to the coherence point (s_waitcnt vmcnt(0)), then
      // RELAXED counter add -- no buffer_wbl2.
      __atomic_signal_fence(__ATOMIC_RELEASE);
      __syncthreads();
      if (tid == 0)
        __hip_atomic_fetch_add(cptr, 1u, __ATOMIC_RELAXED, __HIP_MEMORY_SCOPE_AGENT);
    }
    // ---- out stores for t-1 AFTER the counter add: off the critical path ----
    if (t > 0 && l15 < ncols) {
      #pragma unroll
      for (int r = 0; r < 4; ++r) {
        size_t orow = (size_t)(t - 1) * BB + b0 + quad * 4 + r;
        out[orow * 33 + astart + l15] = oacc[r] + obias;
      }
    }
  }
}

extern "C" void kernel_launch(void* const* d_in, const int* in_sizes, int n_in,
                              void* d_out, int out_size, void* d_ws, size_t ws_size,
                              hipStream_t stream) {
  const float* X       = (const float*)d_in[0];
  const int* is_new    = (const int*)d_in[1];
  const float* carry_c = (const float*)d_in[2];
  const float* carry_h = (const float*)d_in[3];
  const float* Wx      = (const float*)d_in[4];
  const float* Wh      = (const float*)d_in[5];
  const float* b       = (const float*)d_in[6];
  const float* Wa      = (const float*)d_in[7];
  const float* ba      = (const float*)d_in[8];
  const float* Wv      = (const float*)d_in[9];
  const float* bv      = (const float*)d_in[10];
  float* out = (float*)d_out;
  char* ws = (char*)d_ws;
  if (ws_size < WS_NEEDED) return;  // diagnostic: out stays poisoned
  unsigned short* xp   = (unsigned short*)(ws + XP_OFF);
  unsigned short* WxT  = (unsigned short*)(ws + WXT_OFF);
  unsigned short* hbuf = (unsigned short*)(ws + HBUF_OFF);
  unsigned int* cnt    = (unsigned int*)(ws + CNT_OFF);

  hipLaunchKernelGGL(init_sync_kernel, dim3(1), dim3(256), 0, stream, cnt);
  hipLaunchKernelGGL(transpose_wx_kernel, dim3(512), dim3(256), 0, stream, Wx, WxT);
  hipLaunchKernelGGL(gemm_xproj, dim3(8192), dim3(256), 0, stream, X, WxT, b, xp);
  hipLaunchKernelGGL(scan_kernel, dim3(256), dim3(64), 0, stream,
                     xp, is_new, carry_c, carry_h, Wh, Wa, ba, Wv, bv, out, hbuf, cnt);
}

// Round 3
// 2696.308 us; speedup vs baseline: 3.8872x; 1.5831x over previous
//
#include <hip/hip_runtime.h>
#include <hip/hip_bf16.h>
#include <stdint.h>

#define TT 512
#define BB 256
#define DD 512
#define HH 256
#define AA 32
#define NG 1024  // 4*H

using f32x4 = __attribute__((ext_vector_type(4))) float;
using bf8   = __attribute__((ext_vector_type(8))) short;

static __device__ __forceinline__ short f2bf(float f) {
  union { float f; uint32_t u; } v; v.f = f;
  uint32_t u = v.u;
  u = u + 0x7fffu + ((u >> 16) & 1u);   // round-to-nearest-even
  return (short)(u >> 16);
}
static __device__ __forceinline__ float bf2f(unsigned short s) {
  union { uint32_t u; float f; } v; v.u = ((uint32_t)s) << 16;
  return v.f;
}
static __device__ __forceinline__ float sigf(float x) {
  return 1.0f / (1.0f + __expf(-x));
}
static __device__ __forceinline__ float tanh_(float x) {
  float e = __expf(2.0f * x);
  return 1.0f - 2.0f / (e + 1.0f);   // safe at +/-inf
}

// ---- workspace layout ----
static constexpr size_t XP_OFF    = 0;                              // bf16 [T*B][1024]
static constexpr size_t XP_BYTES  = (size_t)TT * BB * NG * 2;       // 268435456
static constexpr size_t WXT_OFF   = XP_OFF + XP_BYTES;              // bf16 [1024][512]
static constexpr size_t WXT_BYTES = (size_t)NG * DD * 2;            // 1048576
// tagged mail: u32 {low16 = bf16 h, high16 = tag = t+1}
// [parity 2][grp 16][half 2][row 16][hcol 128]
static constexpr size_t MAIL_OFF  = WXT_OFF + WXT_BYTES;
static constexpr size_t MAIL_BYTES= (size_t)2 * 16 * 2 * 16 * 128 * 4;  // 524288
static constexpr size_t WS_NEEDED = MAIL_OFF + MAIL_BYTES;
// NOTE: no mail init needed -- harness poisons ws to 0xAA before every launch,
// and poison tag 0xAAAA never equals a valid tag (1..512).

// Wx [512][1024] fp32 -> WxT [1024][512] bf16
__global__ __launch_bounds__(256) void transpose_wx_kernel(
    const float* __restrict__ Wx, unsigned short* __restrict__ WxT) {
  __shared__ float tile[32][33];
  int bx = blockIdx.x;
  int k0 = (bx & 15) * 32;
  int n0 = (bx >> 4) * 32;
  int r = threadIdx.x >> 5;
  int c = threadIdx.x & 31;
  #pragma unroll
  for (int i = 0; i < 4; ++i) {
    int rr = r + i * 8;
    tile[rr][c] = Wx[(size_t)(k0 + rr) * NG + n0 + c];
  }
  __syncthreads();
  #pragma unroll
  for (int i = 0; i < 4; ++i) {
    int rr = r + i * 8;
    WxT[(size_t)(n0 + rr) * DD + k0 + c] = (unsigned short)f2bf(tile[c][rr]);
  }
}

// xp[M=131072][1024] bf16 = X[M][512] @ Wx[512][1024] + b   (unchanged from R2)
__global__ __launch_bounds__(256) void gemm_xproj(
    const float* __restrict__ X,
    const unsigned short* __restrict__ WxT,  // [n][k] bf16
    const float* __restrict__ bias,
    unsigned short* __restrict__ xp) {
  __shared__ short As[128][72];  // [m][k], +8 pad -> 2-way-free banks
  __shared__ short Bs[128][72];  // [n][k]
  const int tid  = threadIdx.x;
  const int lane = tid & 63;
  const int wave = tid >> 6;
  const int quad = lane >> 4;
  const int l15  = lane & 15;
  const int wm = wave >> 1, wn = wave & 1;
  const int bid = blockIdx.x;
  const int m0 = (bid >> 3) * 128;   // consecutive bids share m-tile -> L3 reuse of X
  const int n0 = (bid & 7) * 128;

  f32x4 acc[4][4];
  #pragma unroll
  for (int i = 0; i < 4; ++i)
    #pragma unroll
    for (int j = 0; j < 4; ++j) acc[i][j] = (f32x4){0.f, 0.f, 0.f, 0.f};

  for (int kt = 0; kt < 8; ++kt) {
    const int k0 = kt * 64;
    #pragma unroll
    for (int jj = 0; jj < 4; ++jj) {
      int c = tid + jj * 256;         // 1024 16B-chunks
      int row = c >> 3;
      int kc = (c & 7) * 8;
      const float4* src = (const float4*)(X + (size_t)(m0 + row) * DD + k0 + kc);
      float4 v0 = src[0];
      float4 v1 = src[1];
      bf8 tv;
      tv[0] = f2bf(v0.x); tv[1] = f2bf(v0.y); tv[2] = f2bf(v0.z); tv[3] = f2bf(v0.w);
      tv[4] = f2bf(v1.x); tv[5] = f2bf(v1.y); tv[6] = f2bf(v1.z); tv[7] = f2bf(v1.w);
      *(bf8*)&As[row][kc] = tv;
      const uint4* bsrc = (const uint4*)(WxT + (size_t)(n0 + row) * DD + k0 + kc);
      *(uint4*)&Bs[row][kc] = *bsrc;
    }
    __syncthreads();
    #pragma unroll
    for (int ks = 0; ks < 2; ++ks) {
      bf8 a[4], b[4];
      #pragma unroll
      for (int mt = 0; mt < 4; ++mt)
        a[mt] = *(const bf8*)&As[wm * 64 + mt * 16 + l15][ks * 32 + quad * 8];
      #pragma unroll
      for (int nt = 0; nt < 4; ++nt)
        b[nt] = *(const bf8*)&Bs[wn * 64 + nt * 16 + l15][ks * 32 + quad * 8];
      #pragma unroll
      for (int mt = 0; mt < 4; ++mt)
        #pragma unroll
        for (int nt = 0; nt < 4; ++nt)
          acc[mt][nt] = __builtin_amdgcn_mfma_f32_16x16x32_bf16(a[mt], b[nt], acc[mt][nt], 0, 0, 0);
    }
    __syncthreads();
  }
  #pragma unroll
  for (int mt = 0; mt < 4; ++mt)
    #pragma unroll
    for (int nt = 0; nt < 4; ++nt) {
      int col = n0 + wn * 64 + nt * 16 + l15;
      float bv = bias[col];
      #pragma unroll
      for (int r = 0; r < 4; ++r) {
        int row = m0 + wm * 64 + mt * 16 + quad * 4 + r;  // C/D: row=quad*4+reg, col=lane&15
        xp[(size_t)row * NG + col] = (unsigned short)f2bf(acc[mt][nt][r] + bv);
      }
    }
}

// Persistent scan: 32 blocks = 16 batch-groups x 2 halves, 512 thr (8 waves).
// Wave w of block (grp,p) owns j-slice s = p*8+w (16 h-cols) for batch rows
// [grp*16, grp*16+16). Own half of h stays in LDS; only the partner half
// (4 KB) crosses the fabric, as tagged u32 words {bf16 h | tag=t+1} stored
// with relaxed agent atomics (single-copy atomic: tag travels with payload).
// Consumer polls its own 16 B of mail until tags==t -- no counters, no flags,
// no producer-side drain. ABA on the parity-2 buffers is excluded inductively:
// the partner can't reach iter t+1's stores without having consumed iter-t tags.
__global__ __launch_bounds__(512, 2) void scan_kernel(
    const unsigned short* __restrict__ xp,
    const int* __restrict__ is_new,
    const float* __restrict__ carry_c,
    const float* __restrict__ carry_h,
    const float* __restrict__ Wh,
    const float* __restrict__ Wa,
    const float* __restrict__ ba,
    const float* __restrict__ Wv,
    const float* __restrict__ bv,
    float* __restrict__ out,
    unsigned int* __restrict__ mail) {
  const int tid  = threadIdx.x;
  const int lane = tid & 63;
  const int w    = tid >> 6;          // wave 0..7
  const int quad = (lane >> 4);
  const int l15  = lane & 15;
  const int bid  = blockIdx.x;        // 0..31
  const int grp  = bid >> 1;
  const int p    = bid & 1;           // half
  const int s    = p * 8 + w;         // j-slice 0..15
  const int b0   = grp * 16;
  const int j0   = s * 16;

  __shared__ short h_lds[16][264];    // bf16 full rows, +8 pad
  __shared__ int flag_lds[2][16];     // double-buffered by t&1 (inter-wave race)

  // ---- loop-invariant Wh B-fragments -> 128 VGPRs ----
  bf8 whb[4][8];
  #pragma unroll
  for (int nt = 0; nt < 4; ++nt)
    #pragma unroll
    for (int ks = 0; ks < 8; ++ks)
      #pragma unroll
      for (int j = 0; j < 8; ++j) {
        int k = ks * 32 + quad * 8 + j;            // B-frag: k = quad*8+j, n = lane&15
        int col = nt * 256 + j0 + l15;
        whb[nt][ks][j] = f2bf(Wh[(size_t)k * NG + col]);
      }
  // ---- Wa/Wv B-fragments (head GEMM), cols astart..astart+ncols-1 of 33 ----
  const int astart = (s < 15) ? (2 * s) : 30;
  const int ncols  = (s < 15) ? 2 : 3;
  bf8 wab[8];
  #pragma unroll
  for (int ks = 0; ks < 8; ++ks)
    #pragma unroll
    for (int j = 0; j < 8; ++j) {
      int k = ks * 32 + quad * 8 + j;
      float v = 0.0f;
      if (l15 < ncols) {
        int a = astart + l15;
        v = (a < 32) ? Wa[(size_t)k * 32 + a] : Wv[k];
      }
      wab[ks][j] = f2bf(v);
    }
  float obias = 0.0f;
  if (l15 < ncols) {
    int a = astart + l15;
    obias = (a < 32) ? ba[a] : bv[0];
  }
  // ---- carry c in registers (C-layout: b = quad*4+r, j = j0+l15) ----
  float c4[4];
  #pragma unroll
  for (int r = 0; r < 4; ++r)
    c4[r] = carry_c[(size_t)(b0 + quad * 4 + r) * HH + j0 + l15];

  // consumer-side mail mapping: thread -> (row, 4 consecutive hcols)
  const int crow = tid >> 5;          // 0..15
  const int cc0  = (tid & 31) * 4;    // 0..124

  #pragma unroll 1
  for (int t = 0; t <= TT; ++t) {
    const bool last = (t == TT);
    unsigned short xpraw[16];
    if (!last) {
      // prefetch xp + reset flags before the spin (independent of h)
      #pragma unroll
      for (int nt = 0; nt < 4; ++nt)
        #pragma unroll
        for (int r = 0; r < 4; ++r) {
          size_t row = (size_t)t * BB + b0 + quad * 4 + r;
          xpraw[nt * 4 + r] = xp[row * NG + nt * 256 + j0 + l15];
        }
      if (tid < 16) flag_lds[t & 1][tid] = is_new[t * BB + b0 + tid];
    }
    // ---- acquire partner half: poll own 16B of tagged mail ----
    if (t > 0) {
      unsigned long long* mp = (unsigned long long*)
          (mail + ((((size_t)(t & 1) * 16 + grp) * 2 + (1 - p)) * 2048)
                + (size_t)crow * 128 + cc0);
      const unsigned long long M = 0xFFFF0000FFFF0000ull;
      const unsigned long long Wt = ((unsigned long long)(unsigned)t << 16)
                                  | ((unsigned long long)(unsigned)t << 48);
      unsigned long long pv0, pv1;
      int guard = 0;
      for (;;) {
        pv0 = __hip_atomic_load(&mp[0], __ATOMIC_RELAXED, __HIP_MEMORY_SCOPE_AGENT);
        pv1 = __hip_atomic_load(&mp[1], __ATOMIC_RELAXED, __HIP_MEMORY_SCOPE_AGENT);
        bool ok = ((pv0 & M) == Wt) && ((pv1 & M) == Wt);
        if (__all((int)ok)) break;
        __builtin_amdgcn_s_sleep(1);
        if (++guard > (1 << 24)) break;   // anti-hang bailout
      }
      __atomic_signal_fence(__ATOMIC_ACQUIRE);
      // pack the 4 low shorts -> 8B LDS write of the partner half
      unsigned long long packed =
            (pv0 & 0xFFFFull)
          | (((pv0 >> 32) & 0xFFFFull) << 16)
          | ((pv1 & 0xFFFFull) << 32)
          | (((pv1 >> 32) & 0xFFFFull) << 48);
      *(unsigned long long*)&h_lds[crow][(1 - p) * 128 + cc0] = packed;
    } else {
      // t==0: stage full rows from carry_h (fp32 -> bf16)
      int row  = tid >> 5;
      int col0 = (tid & 31) * 8;
      const float4* src = (const float4*)(carry_h + (size_t)(b0 + row) * HH + col0);
      float4 a = src[0], b4 = src[1];
      bf8 tv;
      tv[0] = f2bf(a.x);  tv[1] = f2bf(a.y);  tv[2] = f2bf(a.z);  tv[3] = f2bf(a.w);
      tv[4] = f2bf(b4.x); tv[5] = f2bf(b4.y); tv[6] = f2bf(b4.z); tv[7] = f2bf(b4.w);
      *(bf8*)&h_lds[row][col0] = tv;
    }
    __syncthreads();   // B2: staging complete (own half persisted from iter t-1)
    // ---- A-fragments of h (m = lane&15 = batch row, k = quad*8+j) ----
    bf8 af[8];
    #pragma unroll
    for (int ks = 0; ks < 8; ++ks)
      af[ks] = *(const bf8*)&h_lds[l15][ks * 32 + quad * 8];
    __syncthreads();   // B3: reads done -> h_lds own-half writable below
    if (!last) {
      // ---- episode reset on h (separate copy: heads use un-reset af) ----
      bf8 afr[8];
      int mreset = flag_lds[t & 1][l15];
      #pragma unroll
      for (int ks = 0; ks < 8; ++ks) {
        afr[ks] = af[ks];
        if (mreset)
          #pragma unroll
          for (int j = 0; j < 8; ++j) afr[ks][j] = 0;
      }
      // ---- z = h @ Wh (4 gate-aligned n-tiles) ----
      f32x4 zacc[4];
      #pragma unroll
      for (int nt = 0; nt < 4; ++nt) zacc[nt] = (f32x4){0.f, 0.f, 0.f, 0.f};
      #pragma unroll
      for (int ks = 0; ks < 8; ++ks)
        #pragma unroll
        for (int nt = 0; nt < 4; ++nt)
          zacc[nt] = __builtin_amdgcn_mfma_f32_16x16x32_bf16(afr[ks], whb[nt][ks], zacc[nt], 0, 0, 0);
      // ---- gates (all four gates of (b,j) live in the same lane/reg) ----
      unsigned int* mout = mail + ((((size_t)((t + 1) & 1) * 16 + grp) * 2 + p) * 2048);
      const unsigned int tag = (unsigned int)(t + 1) << 16;
      #pragma unroll
      for (int r = 0; r < 4; ++r) {
        int fr = flag_lds[t & 1][quad * 4 + r];
        float zi = zacc[0][r] + bf2f(xpraw[0 * 4 + r]);
        float zf = zacc[1][r] + bf2f(xpraw[1 * 4 + r]);
        float zg = zacc[2][r] + bf2f(xpraw[2 * 4 + r]);
        float zo = zacc[3][r] + bf2f(xpraw[3 * 4 + r]);
        float ce = fr ? 0.0f : c4[r];
        float ncv = sigf(zf) * ce + sigf(zi) * tanh_(zg);
        c4[r] = ncv;
        float nh = sigf(zo) * tanh_(ncv);
        unsigned short hv = (unsigned short)f2bf(nh);
        int row = quad * 4 + r;
        h_lds[row][j0 + l15] = (short)hv;                 // own half, block-local
        __hip_atomic_store(&mout[(size_t)row * 128 + w * 16 + l15],
                           (unsigned int)hv | tag,
                           __ATOMIC_RELAXED, __HIP_MEMORY_SCOPE_AGENT);
      }
    }
    // ---- heads + out for step t-1 AFTER the h handoff: off critical path ----
    if (t > 0) {
      f32x4 oacc = {0.f, 0.f, 0.f, 0.f};
      #pragma unroll
      for (int ks = 0; ks < 8; ++ks)
        oacc = __builtin_amdgcn_mfma_f32_16x16x32_bf16(af[ks], wab[ks], oacc, 0, 0, 0);
      if (l15 < ncols) {
        #pragma unroll
        for (int r = 0; r < 4; ++r) {
          size_t orow = (size_t)(t - 1) * BB + b0 + quad * 4 + r;
          out[orow * 33 + astart + l15] = oacc[r] + obias;
        }
      }
    }
  }
}

extern "C" void kernel_launch(void* const* d_in, const int* in_sizes, int n_in,
                              void* d_out, int out_size, void* d_ws, size_t ws_size,
                              hipStream_t stream) {
  const float* X       = (const float*)d_in[0];
  const int* is_new    = (const int*)d_in[1];
  const float* carry_c = (const float*)d_in[2];
  const float* carry_h = (const float*)d_in[3];
  const float* Wx      = (const float*)d_in[4];
  const float* Wh      = (const float*)d_in[5];
  const float* b       = (const float*)d_in[6];
  const float* Wa      = (const float*)d_in[7];
  const float* ba      = (const float*)d_in[8];
  const float* Wv      = (const float*)d_in[9];
  const float* bv      = (const float*)d_in[10];
  float* out = (float*)d_out;
  char* ws = (char*)d_ws;
  if (ws_size < WS_NEEDED) return;  // diagnostic: out stays poisoned
  unsigned short* xp   = (unsigned short*)(ws + XP_OFF);
  unsigned short* WxT  = (unsigned short*)(ws + WXT_OFF);
  unsigned int* mail   = (unsigned int*)(ws + MAIL_OFF);

  hipLaunchKernelGGL(transpose_wx_kernel, dim3(512), dim3(256), 0, stream, Wx, WxT);
  hipLaunchKernelGGL(gemm_xproj, dim3(8192), dim3(256), 0, stream, X, WxT, b, xp);
  hipLaunchKernelGGL(scan_kernel, dim3(32), dim3(512), 0, stream,
                     xp, is_new, carry_c, carry_h, Wh, Wa, ba, Wv, bv, out, mail);
}

// Round 4
// 2487.226 us; speedup vs baseline: 4.2140x; 1.0841x over previous
//
#include <hip/hip_runtime.h>
#include <hip/hip_bf16.h>
#include <stdint.h>

#define TT 512
#define BB 256
#define DD 512
#define HH 256
#define AA 32
#define NG 1024  // 4*H

using f32x4 = __attribute__((ext_vector_type(4))) float;
using bf8   = __attribute__((ext_vector_type(8))) short;

static __device__ __forceinline__ short f2bf(float f) {
  union { float f; uint32_t u; } v; v.f = f;
  uint32_t u = v.u;
  u = u + 0x7fffu + ((u >> 16) & 1u);   // round-to-nearest-even
  return (short)(u >> 16);
}
static __device__ __forceinline__ float bf2f(unsigned short s) {
  union { uint32_t u; float f; } v; v.u = ((uint32_t)s) << 16;
  return v.f;
}
static __device__ __forceinline__ float sigf(float x) {
  return 1.0f / (1.0f + __expf(-x));
}
static __device__ __forceinline__ float tanh_(float x) {
  float e = __expf(2.0f * x);
  return 1.0f - 2.0f / (e + 1.0f);   // safe at +/-inf
}

// ---- workspace layout ----
static constexpr size_t XP_OFF    = 0;                              // bf16 [T*B][1024]
static constexpr size_t XP_BYTES  = (size_t)TT * BB * NG * 2;       // 268435456
static constexpr size_t WXT_OFF   = XP_OFF + XP_BYTES;              // bf16 [1024][512]
static constexpr size_t WXT_BYTES = (size_t)NG * DD * 2;            // 1048576
// tagged mail: u32 {low16 = bf16 h, high16 = tag = t+1}
// [parity 2][grp 16][half 2][row 16][hcol 128]
static constexpr size_t MAIL_OFF  = WXT_OFF + WXT_BYTES;
static constexpr size_t MAIL_BYTES= (size_t)2 * 16 * 2 * 16 * 128 * 4;  // 524288
static constexpr size_t WS_NEEDED = MAIL_OFF + MAIL_BYTES;
// NOTE: no mail init needed -- harness poisons ws to 0xAA before every launch,
// and poison tag 0xAAAA never equals a valid tag (1..512).

// Wx [512][1024] fp32 -> WxT [1024][512] bf16
__global__ __launch_bounds__(256) void transpose_wx_kernel(
    const float* __restrict__ Wx, unsigned short* __restrict__ WxT) {
  __shared__ float tile[32][33];
  int bx = blockIdx.x;
  int k0 = (bx & 15) * 32;
  int n0 = (bx >> 4) * 32;
  int r = threadIdx.x >> 5;
  int c = threadIdx.x & 31;
  #pragma unroll
  for (int i = 0; i < 4; ++i) {
    int rr = r + i * 8;
    tile[rr][c] = Wx[(size_t)(k0 + rr) * NG + n0 + c];
  }
  __syncthreads();
  #pragma unroll
  for (int i = 0; i < 4; ++i) {
    int rr = r + i * 8;
    WxT[(size_t)(n0 + rr) * DD + k0 + c] = (unsigned short)f2bf(tile[c][rr]);
  }
}

// xp[M=131072][1024] bf16 = X[M][512] @ Wx[512][1024] + b   (unchanged)
__global__ __launch_bounds__(256) void gemm_xproj(
    const float* __restrict__ X,
    const unsigned short* __restrict__ WxT,  // [n][k] bf16
    const float* __restrict__ bias,
    unsigned short* __restrict__ xp) {
  __shared__ short As[128][72];  // [m][k], +8 pad -> 2-way-free banks
  __shared__ short Bs[128][72];  // [n][k]
  const int tid  = threadIdx.x;
  const int lane = tid & 63;
  const int wave = tid >> 6;
  const int quad = lane >> 4;
  const int l15  = lane & 15;
  const int wm = wave >> 1, wn = wave & 1;
  const int bid = blockIdx.x;
  const int m0 = (bid >> 3) * 128;   // consecutive bids share m-tile -> L3 reuse of X
  const int n0 = (bid & 7) * 128;

  f32x4 acc[4][4];
  #pragma unroll
  for (int i = 0; i < 4; ++i)
    #pragma unroll
    for (int j = 0; j < 4; ++j) acc[i][j] = (f32x4){0.f, 0.f, 0.f, 0.f};

  for (int kt = 0; kt < 8; ++kt) {
    const int k0 = kt * 64;
    #pragma unroll
    for (int jj = 0; jj < 4; ++jj) {
      int c = tid + jj * 256;         // 1024 16B-chunks
      int row = c >> 3;
      int kc = (c & 7) * 8;
      const float4* src = (const float4*)(X + (size_t)(m0 + row) * DD + k0 + kc);
      float4 v0 = src[0];
      float4 v1 = src[1];
      bf8 tv;
      tv[0] = f2bf(v0.x); tv[1] = f2bf(v0.y); tv[2] = f2bf(v0.z); tv[3] = f2bf(v0.w);
      tv[4] = f2bf(v1.x); tv[5] = f2bf(v1.y); tv[6] = f2bf(v1.z); tv[7] = f2bf(v1.w);
      *(bf8*)&As[row][kc] = tv;
      const uint4* bsrc = (const uint4*)(WxT + (size_t)(n0 + row) * DD + k0 + kc);
      *(uint4*)&Bs[row][kc] = *bsrc;
    }
    __syncthreads();
    #pragma unroll
    for (int ks = 0; ks < 2; ++ks) {
      bf8 a[4], b[4];
      #pragma unroll
      for (int mt = 0; mt < 4; ++mt)
        a[mt] = *(const bf8*)&As[wm * 64 + mt * 16 + l15][ks * 32 + quad * 8];
      #pragma unroll
      for (int nt = 0; nt < 4; ++nt)
        b[nt] = *(const bf8*)&Bs[wn * 64 + nt * 16 + l15][ks * 32 + quad * 8];
      #pragma unroll
      for (int mt = 0; mt < 4; ++mt)
        #pragma unroll
        for (int nt = 0; nt < 4; ++nt)
          acc[mt][nt] = __builtin_amdgcn_mfma_f32_16x16x32_bf16(a[mt], b[nt], acc[mt][nt], 0, 0, 0);
    }
    __syncthreads();
  }
  #pragma unroll
  for (int mt = 0; mt < 4; ++mt)
    #pragma unroll
    for (int nt = 0; nt < 4; ++nt) {
      int col = n0 + wn * 64 + nt * 16 + l15;
      float bv = bias[col];
      #pragma unroll
      for (int r = 0; r < 4; ++r) {
        int row = m0 + wm * 64 + mt * 16 + quad * 4 + r;  // C/D: row=quad*4+reg, col=lane&15
        xp[(size_t)row * NG + col] = (unsigned short)f2bf(acc[mt][nt][r] + bv);
      }
    }
}

// Persistent scan: 32 blocks = 16 batch-groups x 2 halves, 512 thr (8 waves).
// __launch_bounds__(512, 1): min-blocks arg 1 -> VGPR cap 256 (arg 2 capped at
// 128 and SPILLED the 128-reg whb fragments to scratch -- the R3 9.4k-cyc/step
// pathology). Episode reset is applied at the GATE level (zeroed h-rows of A
// <=> dropping the h@Wh term), deleting the afr copy: peak liveness ~240 regs.
__global__ __launch_bounds__(512, 1) void scan_kernel(
    const unsigned short* __restrict__ xp,
    const int* __restrict__ is_new,
    const float* __restrict__ carry_c,
    const float* __restrict__ carry_h,
    const float* __restrict__ Wh,
    const float* __restrict__ Wa,
    const float* __restrict__ ba,
    const float* __restrict__ Wv,
    const float* __restrict__ bv,
    float* __restrict__ out,
    unsigned int* __restrict__ mail) {
  const int tid  = threadIdx.x;
  const int lane = tid & 63;
  const int w    = tid >> 6;          // wave 0..7
  const int quad = (lane >> 4);
  const int l15  = lane & 15;
  const int bid  = blockIdx.x;        // 0..31
  const int grp  = bid >> 1;
  const int p    = bid & 1;           // half
  const int s    = p * 8 + w;         // j-slice 0..15
  const int b0   = grp * 16;
  const int j0   = s * 16;

  __shared__ short h_lds[16][264];    // bf16 full rows, +8 pad
  __shared__ int flag_lds[2][16];     // double-buffered by t&1 (inter-wave race)

  // ---- loop-invariant Wh B-fragments -> 128 VGPRs ----
  bf8 whb[4][8];
  #pragma unroll
  for (int nt = 0; nt < 4; ++nt)
    #pragma unroll
    for (int ks = 0; ks < 8; ++ks)
      #pragma unroll
      for (int j = 0; j < 8; ++j) {
        int k = ks * 32 + quad * 8 + j;            // B-frag: k = quad*8+j, n = lane&15
        int col = nt * 256 + j0 + l15;
        whb[nt][ks][j] = f2bf(Wh[(size_t)k * NG + col]);
      }
  // ---- Wa/Wv B-fragments (head GEMM), cols astart..astart+ncols-1 of 33 ----
  const int astart = (s < 15) ? (2 * s) : 30;
  const int ncols  = (s < 15) ? 2 : 3;
  bf8 wab[8];
  #pragma unroll
  for (int ks = 0; ks < 8; ++ks)
    #pragma unroll
    for (int j = 0; j < 8; ++j) {
      int k = ks * 32 + quad * 8 + j;
      float v = 0.0f;
      if (l15 < ncols) {
        int a = astart + l15;
        v = (a < 32) ? Wa[(size_t)k * 32 + a] : Wv[k];
      }
      wab[ks][j] = f2bf(v);
    }
  float obias = 0.0f;
  if (l15 < ncols) {
    int a = astart + l15;
    obias = (a < 32) ? ba[a] : bv[0];
  }
  // ---- carry c in registers (C-layout: b = quad*4+r, j = j0+l15) ----
  float c4[4];
  #pragma unroll
  for (int r = 0; r < 4; ++r)
    c4[r] = carry_c[(size_t)(b0 + quad * 4 + r) * HH + j0 + l15];

  // consumer-side mail mapping: thread -> (row, 4 consecutive hcols)
  const int crow = tid >> 5;          // 0..15
  const int cc0  = (tid & 31) * 4;    // 0..124

  #pragma unroll 1
  for (int t = 0; t <= TT; ++t) {
    const bool last = (t == TT);
    unsigned short xpraw[16];
    if (!last) {
      // prefetch xp + reset flags before the spin (independent of h)
      #pragma unroll
      for (int nt = 0; nt < 4; ++nt)
        #pragma unroll
        for (int r = 0; r < 4; ++r) {
          size_t row = (size_t)t * BB + b0 + quad * 4 + r;
          xpraw[nt * 4 + r] = xp[row * NG + nt * 256 + j0 + l15];
        }
      if (tid < 16) flag_lds[t & 1][tid] = is_new[t * BB + b0 + tid];
    }
    // ---- acquire partner half: poll own 16B of tagged mail ----
    if (t > 0) {
      unsigned long long* mp = (unsigned long long*)
          (mail + ((((size_t)(t & 1) * 16 + grp) * 2 + (1 - p)) * 2048)
                + (size_t)crow * 128 + cc0);
      const unsigned long long M = 0xFFFF0000FFFF0000ull;
      const unsigned long long Wt = ((unsigned long long)(unsigned)t << 16)
                                  | ((unsigned long long)(unsigned)t << 48);
      unsigned long long pv0, pv1;
      int guard = 0;
      for (;;) {
        pv0 = __hip_atomic_load(&mp[0], __ATOMIC_RELAXED, __HIP_MEMORY_SCOPE_AGENT);
        pv1 = __hip_atomic_load(&mp[1], __ATOMIC_RELAXED, __HIP_MEMORY_SCOPE_AGENT);
        bool ok = ((pv0 & M) == Wt) && ((pv1 & M) == Wt);
        if (__all((int)ok)) break;
        __builtin_amdgcn_s_sleep(1);
        if (++guard > (1 << 24)) break;   // anti-hang bailout
      }
      __atomic_signal_fence(__ATOMIC_ACQUIRE);
      // pack the 4 low shorts -> 8B LDS write of the partner half
      unsigned long long packed =
            (pv0 & 0xFFFFull)
          | (((pv0 >> 32) & 0xFFFFull) << 16)
          | ((pv1 & 0xFFFFull) << 32)
          | (((pv1 >> 32) & 0xFFFFull) << 48);
      *(unsigned long long*)&h_lds[crow][(1 - p) * 128 + cc0] = packed;
    } else {
      // t==0: stage full rows from carry_h (fp32 -> bf16)
      int row  = tid >> 5;
      int col0 = (tid & 31) * 8;
      const float4* src = (const float4*)(carry_h + (size_t)(b0 + row) * HH + col0);
      float4 a = src[0], b4 = src[1];
      bf8 tv;
      tv[0] = f2bf(a.x);  tv[1] = f2bf(a.y);  tv[2] = f2bf(a.z);  tv[3] = f2bf(a.w);
      tv[4] = f2bf(b4.x); tv[5] = f2bf(b4.y); tv[6] = f2bf(b4.z); tv[7] = f2bf(b4.w);
      *(bf8*)&h_lds[row][col0] = tv;
    }
    __syncthreads();   // B2: staging complete (own half persisted from iter t-1)
    // ---- A-fragments of h (m = lane&15 = batch row, k = quad*8+j) ----
    bf8 af[8];
    #pragma unroll
    for (int ks = 0; ks < 8; ++ks)
      af[ks] = *(const bf8*)&h_lds[l15][ks * 32 + quad * 8];
    __syncthreads();   // B3: reads done -> h_lds own-half writable below
    if (!last) {
      // ---- z = h @ Wh (4 gate-aligned n-tiles), UN-reset h ----
      f32x4 zacc[4];
      #pragma unroll
      for (int nt = 0; nt < 4; ++nt) zacc[nt] = (f32x4){0.f, 0.f, 0.f, 0.f};
      #pragma unroll
      for (int ks = 0; ks < 8; ++ks)
        #pragma unroll
        for (int nt = 0; nt < 4; ++nt)
          zacc[nt] = __builtin_amdgcn_mfma_f32_16x16x32_bf16(af[ks], whb[nt][ks], zacc[nt], 0, 0, 0);
      // ---- gates; episode reset folded in: zeroed h-row <=> drop h@Wh term ----
      unsigned int* mout = mail + ((((size_t)((t + 1) & 1) * 16 + grp) * 2 + p) * 2048);
      const unsigned int tag = (unsigned int)(t + 1) << 16;
      #pragma unroll
      for (int r = 0; r < 4; ++r) {
        int fr = flag_lds[t & 1][quad * 4 + r];
        float zi = (fr ? 0.0f : zacc[0][r]) + bf2f(xpraw[0 * 4 + r]);
        float zf = (fr ? 0.0f : zacc[1][r]) + bf2f(xpraw[1 * 4 + r]);
        float zg = (fr ? 0.0f : zacc[2][r]) + bf2f(xpraw[2 * 4 + r]);
        float zo = (fr ? 0.0f : zacc[3][r]) + bf2f(xpraw[3 * 4 + r]);
        float ce = fr ? 0.0f : c4[r];
        float ncv = sigf(zf) * ce + sigf(zi) * tanh_(zg);
        c4[r] = ncv;
        float nh = sigf(zo) * tanh_(ncv);
        unsigned short hv = (unsigned short)f2bf(nh);
        int row = quad * 4 + r;
        h_lds[row][j0 + l15] = (short)hv;                 // own half, block-local
        __hip_atomic_store(&mout[(size_t)row * 128 + w * 16 + l15],
                           (unsigned int)hv | tag,
                           __ATOMIC_RELAXED, __HIP_MEMORY_SCOPE_AGENT);
      }
    }
    // ---- heads + out for step t-1 AFTER the h handoff: off critical path ----
    if (t > 0) {
      f32x4 oacc = {0.f, 0.f, 0.f, 0.f};
      #pragma unroll
      for (int ks = 0; ks < 8; ++ks)
        oacc = __builtin_amdgcn_mfma_f32_16x16x32_bf16(af[ks], wab[ks], oacc, 0, 0, 0);
      if (l15 < ncols) {
        #pragma unroll
        for (int r = 0; r < 4; ++r) {
          size_t orow = (size_t)(t - 1) * BB + b0 + quad * 4 + r;
          out[orow * 33 + astart + l15] = oacc[r] + obias;
        }
      }
    }
  }
}

extern "C" void kernel_launch(void* const* d_in, const int* in_sizes, int n_in,
                              void* d_out, int out_size, void* d_ws, size_t ws_size,
                              hipStream_t stream) {
  const float* X       = (const float*)d_in[0];
  const int* is_new    = (const int*)d_in[1];
  const float* carry_c = (const float*)d_in[2];
  const float* carry_h = (const float*)d_in[3];
  const float* Wx      = (const float*)d_in[4];
  const float* Wh      = (const float*)d_in[5];
  const float* b       = (const float*)d_in[6];
  const float* Wa      = (const float*)d_in[7];
  const float* ba      = (const float*)d_in[8];
  const float* Wv      = (const float*)d_in[9];
  const float* bv      = (const float*)d_in[10];
  float* out = (float*)d_out;
  char* ws = (char*)d_ws;
  if (ws_size < WS_NEEDED) return;  // diagnostic: out stays poisoned
  unsigned short* xp   = (unsigned short*)(ws + XP_OFF);
  unsigned short* WxT  = (unsigned short*)(ws + WXT_OFF);
  unsigned int* mail   = (unsigned int*)(ws + MAIL_OFF);

  hipLaunchKernelGGL(transpose_wx_kernel, dim3(512), dim3(256), 0, stream, Wx, WxT);
  hipLaunchKernelGGL(gemm_xproj, dim3(8192), dim3(256), 0, stream, X, WxT, b, xp);
  hipLaunchKernelGGL(scan_kernel, dim3(32), dim3(512), 0, stream,
                     xp, is_new, carry_c, carry_h, Wh, Wa, ba, Wv, bv, out, mail);
}